// Round 10
// baseline (239.539 us; speedup 1.0000x reference)
//
#include <hip/hip_runtime.h>
#include <hip/hip_bf16.h>

typedef __bf16 bf16x8 __attribute__((ext_vector_type(8)));
typedef __bf16 bf16x4 __attribute__((ext_vector_type(4)));
typedef float  f32x4  __attribute__((ext_vector_type(4)));
typedef float  f32x16 __attribute__((ext_vector_type(16)));

#define GPTR(p) ((__attribute__((address_space(1))) void*)(p))
#define LPTR(p) ((__attribute__((address_space(3))) void*)(p))

// ---------------------------------------------------------------------------
// D1: cvt F_w (512) | transpose-cvt G_w (256) | gemv b2 = F_w@G_b + F_b (1024)
// (R8-proven. Gt is REQUIRED: W[o][k] = sum_h F[o][h]*G[h][k] needs G columns.)
// ---------------------------------------------------------------------------
__global__ __launch_bounds__(256) void pre_kernel(
    const float* __restrict__ Fw, __bf16* __restrict__ f_bf,
    const float* __restrict__ Gw, __bf16* __restrict__ gt_bf,
    const float* __restrict__ Gb, const float* __restrict__ Fb,
    float* __restrict__ b2, int H) {
    __shared__ float tile[64][65];
    const int blk = blockIdx.x;
    const int t = threadIdx.x;

    if (blk < 512) {                       // cvt F_w
        long i = ((long)blk * 256 + t) * 8;
        float4 a = *reinterpret_cast<const float4*>(Fw + i);
        float4 c = *reinterpret_cast<const float4*>(Fw + i + 4);
        bf16x8 o;
        o[0] = (__bf16)a.x; o[1] = (__bf16)a.y; o[2] = (__bf16)a.z; o[3] = (__bf16)a.w;
        o[4] = (__bf16)c.x; o[5] = (__bf16)c.y; o[6] = (__bf16)c.z; o[7] = (__bf16)c.w;
        *reinterpret_cast<bf16x8*>(f_bf + i) = o;
    } else if (blk < 768) {                // transpose-cvt G_w: gt[k][h] = G[h][k]
        const int id = blk - 512;
        const int bx = (id & 15) * 64;
        const int by = (id >> 4) * 64;
        const int tr = t >> 4;
        const int tc = (t & 15) * 4;
#pragma unroll
        for (int i = 0; i < 4; i++) {
            float4 v = *reinterpret_cast<const float4*>(&Gw[(size_t)(by + tr + i * 16) * H + bx + tc]);
            tile[tr + i * 16][tc + 0] = v.x;
            tile[tr + i * 16][tc + 1] = v.y;
            tile[tr + i * 16][tc + 2] = v.z;
            tile[tr + i * 16][tc + 3] = v.w;
        }
        __syncthreads();
        const int wr = t >> 2;
        const int wc = (t & 3) * 16;
        bf16x8 o0, o1;
#pragma unroll
        for (int j = 0; j < 8; j++) o0[j] = (__bf16)tile[wc + j][wr];
#pragma unroll
        for (int j = 0; j < 8; j++) o1[j] = (__bf16)tile[wc + 8 + j][wr];
        *reinterpret_cast<bf16x8*>(&gt_bf[(size_t)(bx + wr) * H + by + wc]) = o0;
        *reinterpret_cast<bf16x8*>(&gt_bf[(size_t)(bx + wr) * H + by + wc + 8]) = o1;
    } else {                               // gemv b2[o] = Fw[o,:]·Gb + Fb[o]
        const int o = blk - 768;
        float s = 0.f;
        for (int h = t; h < H; h += 256) s += Fw[(size_t)o * H + h] * Gb[h];
#pragma unroll
        for (int off = 32; off > 0; off >>= 1) s += __shfl_xor(s, off);
        __shared__ float ss[4];
        if ((t & 63) == 0) ss[t >> 6] = s;
        __syncthreads();
        if (t == 0) b2[o] = ss[0] + ss[1] + ss[2] + ss[3] + Fb[o];
    }
}

// ---------------------------------------------------------------------------
// D2 (independent, R8-proven): GEMM0 W[o][k]=sum_h F[o][h]*Gt[k][h] (0..255) |
// transpose-cvt hidden -> Xt[b][h][s] (256..2303) | softmax (2304..10495)
// ---------------------------------------------------------------------------
__global__ __launch_bounds__(256) void mid_kernel(
    const __bf16* __restrict__ f_bf, const __bf16* __restrict__ gt_bf,
    __bf16* __restrict__ Wm,
    const float* __restrict__ hidden, __bf16* __restrict__ xt,
    const float* __restrict__ R, const float* __restrict__ mask,
    __bf16* __restrict__ P, int H, int S) {
    const int blk = blockIdx.x;
    const int t = threadIdx.x;

    if (blk < 256) {  // GEMM0 64x64 tile: C[m=o][n=k], direct write Wm[o][k]
        __shared__ __bf16 As[64 * 64];
        __shared__ __bf16 Bs[64 * 64];
        const int lane = t & 63;
        const int wave = t >> 6;
        const int lane31 = lane & 31;
        const int hi = lane >> 5;
        const int wm = (wave >> 1) * 32;
        const int wn = (wave & 1) * 32;
        const int bm = (blk >> 4) * 64;
        const int bn = (blk & 15) * 64;

        const int rsub = lane >> 3;
        const int csub = lane & 7;
        const int lchunk = csub ^ rsub;
        const __bf16* ga0 = f_bf + (size_t)(bm + wave * 16 + rsub) * H + lchunk * 8;
        const __bf16* gb0 = gt_bf + (size_t)(bn + wave * 16 + rsub) * H + lchunk * 8;

        f32x16 acc = (f32x16)(0.f);
        for (int kt = 0; kt < H; kt += 64) {
            __syncthreads();
#pragma unroll
            for (int c = 0; c < 2; c++)
                __builtin_amdgcn_global_load_lds(GPTR(ga0 + (size_t)(c * 8) * H + kt),
                                                 LPTR(&As[(wave * 16 + c * 8) * 64]), 16, 0, 0);
#pragma unroll
            for (int c = 0; c < 2; c++)
                __builtin_amdgcn_global_load_lds(GPTR(gb0 + (size_t)(c * 8) * H + kt),
                                                 LPTR(&Bs[(wave * 16 + c * 8) * 64]), 16, 0, 0);
            __syncthreads();
#pragma unroll
            for (int s = 0; s < 4; s++) {
                const int ra = wm + lane31;
                const int rb = wn + lane31;
                bf16x8 af = *reinterpret_cast<const bf16x8*>(
                    &As[ra * 64 + (((2 * s + hi) ^ (ra & 7)) << 3)]);
                bf16x8 bfr = *reinterpret_cast<const bf16x8*>(
                    &Bs[rb * 64 + (((2 * s + hi) ^ (rb & 7)) << 3)]);
                acc = __builtin_amdgcn_mfma_f32_32x32x16_bf16(af, bfr, acc, 0, 0, 0);
            }
        }
        const int cm = bm + wm;
        const int cn = bn + wn + lane31;
#pragma unroll
        for (int rq = 0; rq < 4; rq++) {
            const int rbase = rq * 8 + 4 * hi;
#pragma unroll
            for (int rr = 0; rr < 4; rr++)
                Wm[(size_t)(cm + rbase + rr) * H + cn] = (__bf16)acc[rq * 4 + rr];
        }
    } else if (blk < 2304) {  // transpose-cvt hidden[b]: Xt[b][h][s]
        __shared__ float tile[64][65];
        const int id = blk - 256;
        const int b = id >> 9;
        const int tid = id & 511;
        const int by = (tid >> 4) * 64;    // s-base
        const int bx = (tid & 15) * 64;    // h-base
        const float* x = hidden + (size_t)b * S * H;
        __bf16* y = xt + (size_t)b * H * S;
        const int tr = t >> 4;
        const int tc = (t & 15) * 4;
#pragma unroll
        for (int i = 0; i < 4; i++) {
            float4 v = *reinterpret_cast<const float4*>(&x[(size_t)(by + tr + i * 16) * H + bx + tc]);
            tile[tr + i * 16][tc + 0] = v.x;
            tile[tr + i * 16][tc + 1] = v.y;
            tile[tr + i * 16][tc + 2] = v.z;
            tile[tr + i * 16][tc + 3] = v.w;
        }
        __syncthreads();
        const int wr = t >> 2;
        const int wc = (t & 3) * 16;
        bf16x8 o0, o1;
#pragma unroll
        for (int j = 0; j < 8; j++) o0[j] = (__bf16)tile[wc + j][wr];
#pragma unroll
        for (int j = 0; j < 8; j++) o1[j] = (__bf16)tile[wc + 8 + j][wr];
        *reinterpret_cast<bf16x8*>(&y[(size_t)(bx + wr) * S + by + wc]) = o0;
        *reinterpret_cast<bf16x8*>(&y[(size_t)(bx + wr) * S + by + wc + 8]) = o1;
    } else {          // softmax row
        const int id = blk - 2304;
        const int b = id >> 11;
        const int q = id & 2047;
        const int lane = t & 63, wave = t >> 6;
        const float* rrow = R + (size_t)q * S;
        const float* mrow = mask + ((size_t)b * S + q) * (size_t)S;
        __bf16* prow = P + ((size_t)b * S + q) * (size_t)S;

        float v[8];
#pragma unroll
        for (int i = 0; i < 2; i++) {
            float4 r4 = *reinterpret_cast<const float4*>(rrow + t * 8 + i * 4);
            float4 m4 = *reinterpret_cast<const float4*>(mrow + t * 8 + i * 4);
            v[i * 4 + 0] = r4.x + m4.x;
            v[i * 4 + 1] = r4.y + m4.y;
            v[i * 4 + 2] = r4.z + m4.z;
            v[i * 4 + 3] = r4.w + m4.w;
        }
        float mx = v[0];
#pragma unroll
        for (int i = 1; i < 8; i++) mx = fmaxf(mx, v[i]);
#pragma unroll
        for (int off = 32; off > 0; off >>= 1) mx = fmaxf(mx, __shfl_xor(mx, off));
        __shared__ float smax[4], ssum[4];
        if (lane == 0) smax[wave] = mx;
        __syncthreads();
        mx = fmaxf(fmaxf(smax[0], smax[1]), fmaxf(smax[2], smax[3]));
        float sum = 0.f;
#pragma unroll
        for (int i = 0; i < 8; i++) { v[i] = __expf(v[i] - mx); sum += v[i]; }
#pragma unroll
        for (int off = 32; off > 0; off >>= 1) sum += __shfl_xor(sum, off);
        if (lane == 0) ssum[wave] = sum;
        __syncthreads();
        sum = ssum[0] + ssum[1] + ssum[2] + ssum[3];
        const float inv = 1.0f / sum;
        bf16x8 o;
#pragma unroll
        for (int i = 0; i < 8; i++) o[i] = (__bf16)(v[i] * inv);
        *reinterpret_cast<bf16x8*>(prow + t * 8) = o;
    }
}

// ---------------------------------------------------------------------------
// NT GEMM, 16x16-frag variant (conflict experiment): C[m,n] = sum_k A[m,k]*
// B[n,k] (+ bias[n]). 64(M) x 128(N) tile, BK=64, 128 threads = 2 waves; wave
// w covers n = w*64..+63 as 4x4 of mfma_f32_16x16x32 (64 acc VGPRs).
// R2's 16x16 frag-read measured 0 LDS conflicts; every 32x32 variant measured
// exactly 2^22. Same staging, same LDS bytes — only the read pattern differs.
// Frag: row = tile + idx*16 + lane16, k = s*32 + quad*8 + j.
// Staging: global_load_lds w16, XOR chunks (phys = logical ^ (row&7)).
// SWZMODE 1 (T1): id&7 = XCD -> (b, m-half); SWZMODE 2 (T2): id&7 -> m-range.
// ---------------------------------------------------------------------------
template <bool CFLOAT, bool BIAS, int SWZMODE>
__global__ __launch_bounds__(128) void gemm16_nt_kernel(
    const __bf16* __restrict__ A, const __bf16* __restrict__ B,
    const float* __restrict__ bias, void* __restrict__ Cv,
    int K, int lda, int ldb, int ldc,
    long strideA, long strideB, long strideC) {
    const int t = threadIdx.x;
    const int lane = t & 63;
    const int wave = t >> 6;             // 0/1, n-half
    const int lane16 = lane & 15;
    const int quad = lane >> 4;
    int bm, bn, bz;
    if constexpr (SWZMODE == 1) {
        const int id = blockIdx.x;
        const int xcd = id & 7;
        const int slot = id >> 3;
        bz = xcd >> 1;
        bm = ((xcd & 1) * 16 + (slot >> 3)) * 64;
        bn = (slot & 7) * 128;
    } else {
        const int id = blockIdx.x;
        const int xcd = id & 7;
        const int slot = id >> 3;
        bz = 0;
        bm = (xcd * 16 + (slot >> 3)) * 64;
        bn = (slot & 7) * 128;
    }

    A += (size_t)bz * strideA;
    B += (size_t)bz * strideB;

    __shared__ __bf16 smem[12288];       // 24 KB: As 64x64 | Bs 128x64
    __bf16* const As = smem;
    __bf16* const Bs = smem + 4096;

    // staging: wave w -> A rows w*32..+31 (4 DMAs), B rows w*64..+63 (8 DMAs)
    const int rsub = lane >> 3;
    const int csub = lane & 7;
    const int lchunk = csub ^ rsub;
    const __bf16* ga0 = A + (size_t)(bm + wave * 32 + rsub) * lda + lchunk * 8;
    const __bf16* gb0 = B + (size_t)(bn + wave * 64 + rsub) * ldb + lchunk * 8;

    f32x4 acc[4][4];
#pragma unroll
    for (int i = 0; i < 4; i++)
#pragma unroll
        for (int j = 0; j < 4; j++) acc[i][j] = (f32x4){0.f, 0.f, 0.f, 0.f};

    for (int kt = 0; kt < K; kt += 64) {
        __syncthreads();
#pragma unroll
        for (int c = 0; c < 4; c++)
            __builtin_amdgcn_global_load_lds(GPTR(ga0 + (size_t)(c * 8) * lda + kt),
                                             LPTR(&As[(wave * 32 + c * 8) * 64]), 16, 0, 0);
#pragma unroll
        for (int c = 0; c < 8; c++)
            __builtin_amdgcn_global_load_lds(GPTR(gb0 + (size_t)(c * 8) * ldb + kt),
                                             LPTR(&Bs[(wave * 64 + c * 8) * 64]), 16, 0, 0);
        __syncthreads();
#pragma unroll
        for (int s = 0; s < 2; s++) {    // two k32-steps
            bf16x8 af[4], bfr[4];
#pragma unroll
            for (int mi = 0; mi < 4; mi++) {
                const int r = mi * 16 + lane16;
                af[mi] = *reinterpret_cast<const bf16x8*>(
                    &As[r * 64 + (((s * 4 + quad) ^ (r & 7)) << 3)]);
            }
#pragma unroll
            for (int ni = 0; ni < 4; ni++) {
                const int r = wave * 64 + ni * 16 + lane16;
                bfr[ni] = *reinterpret_cast<const bf16x8*>(
                    &Bs[r * 64 + (((s * 4 + quad) ^ (r & 7)) << 3)]);
            }
#pragma unroll
            for (int mi = 0; mi < 4; mi++)
#pragma unroll
                for (int ni = 0; ni < 4; ni++)
                    acc[mi][ni] = __builtin_amdgcn_mfma_f32_16x16x32_bf16(af[mi], bfr[ni], acc[mi][ni], 0, 0, 0);
        }
    }

    // Epilogue. C/D (16x16): col = lane16, row = quad*4 + reg  [m89/m91]
    __bf16* Cb = (__bf16*)Cv + (size_t)bz * strideC;
    float* Cf = (float*)Cv + (size_t)bz * strideC;
#pragma unroll
    for (int mi = 0; mi < 4; mi++)
#pragma unroll
        for (int ni = 0; ni < 4; ni++) {
            const int cm = bm + mi * 16 + quad * 4;
            const int cn = bn + wave * 64 + ni * 16 + lane16;
            const float bv = BIAS ? bias[cn] : 0.0f;
#pragma unroll
            for (int rr = 0; rr < 4; rr++) {
                if constexpr (CFLOAT)
                    Cf[(size_t)(cm + rr) * ldc + cn] = acc[mi][ni][rr] + bv;
                else
                    Cb[(size_t)(cm + rr) * ldc + cn] = (__bf16)(acc[mi][ni][rr] + bv);
            }
        }
}

// ---------------------------------------------------------------------------
// Pipeline (out = (P @ X) W^T + b2, W = F G, b2 = F G_b + F_b):
//   D1[cvtF|transpG|gemv] -> D2[GEMM0->W || transp-hidden || softmax]
//   -> T1 = P @ Xt (bf16) -> T2 = T1 @ W^T + b2 (fp32)
// ---------------------------------------------------------------------------
extern "C" void kernel_launch(void* const* d_in, const int* in_sizes, int n_in,
                              void* d_out, int out_size, void* d_ws, size_t ws_size,
                              hipStream_t stream) {
    const float* hidden = (const float*)d_in[0];
    const float* mask   = (const float*)d_in[1];
    const float* R      = (const float*)d_in[2];
    const float* G_w    = (const float*)d_in[3];
    const float* G_b    = (const float*)d_in[4];
    const float* F_w    = (const float*)d_in[5];
    const float* F_b    = (const float*)d_in[6];
    float* out = (float*)d_out;

    constexpr int B = 4, S = 2048, H = 1024;
    char* ws = (char*)d_ws;
    __bf16* xt    = (__bf16*)(ws);                   // 16 MB  Xt[b][h][s]
    __bf16* t1    = (__bf16*)(ws + (16ll << 20));    // 16 MB  T1[b][q][h]
    __bf16* probs = (__bf16*)(ws + (32ll << 20));    // 32 MB
    __bf16* f_bf  = (__bf16*)(ws + (64ll << 20));    // 2 MB
    __bf16* gt_bf = (__bf16*)(ws + (66ll << 20));    // 2 MB
    __bf16* Wm    = (__bf16*)(ws + (68ll << 20));    // 2 MB
    float*  b2    = (float*)(ws + (70ll << 20));     // 4 KB

    pre_kernel<<<1792, 256, 0, stream>>>(F_w, f_bf, G_w, gt_bf, G_b, F_b, b2, H);

    mid_kernel<<<10496, 256, 0, stream>>>(f_bf, gt_bf, Wm, hidden, xt,
                                          R, mask, probs, H, S);

    // T1[b][q][h] = sum_s probs[b][q][s] * Xt[b][h][s]   (bf16 out, XCD swizzle)
    gemm16_nt_kernel<false, false, 1><<<1024, 128, 0, stream>>>(
        probs, xt, nullptr, t1, S, S, S, H,
        (long)S * S, (long)H * S, (long)S * H);

    // out[m][o] = sum_h T1[m][h] * W[o][h] + b2[o]   (m = b*S+q flat, fp32 out)
    gemm16_nt_kernel<true, true, 2><<<1024, 128, 0, stream>>>(
        t1, Wm, b2, out, H, H, H, H, 0, 0, 0);
}

// Round 11
// 225.430 us; speedup vs baseline: 1.0626x; 1.0626x over previous
//
#include <hip/hip_runtime.h>
#include <hip/hip_bf16.h>

typedef __bf16 bf16x8 __attribute__((ext_vector_type(8)));
typedef __bf16 bf16x4 __attribute__((ext_vector_type(4)));
typedef float  f32x16 __attribute__((ext_vector_type(16)));

#define GPTR(p) ((__attribute__((address_space(1))) void*)(p))
#define LPTR(p) ((__attribute__((address_space(3))) void*)(p))

// ---------------------------------------------------------------------------
// D1: cvt F_w (512) | transpose-cvt G_w (256) | gemv b2 = F_w@G_b + F_b (1024)
// (Gt REQUIRED: W[o][k] = sum_h F[o][h]*G[h][k] needs G columns.)
// ---------------------------------------------------------------------------
__global__ __launch_bounds__(256) void pre_kernel(
    const float* __restrict__ Fw, __bf16* __restrict__ f_bf,
    const float* __restrict__ Gw, __bf16* __restrict__ gt_bf,
    const float* __restrict__ Gb, const float* __restrict__ Fb,
    float* __restrict__ b2, int H) {
    __shared__ float tile[64][65];
    const int blk = blockIdx.x;
    const int t = threadIdx.x;

    if (blk < 512) {                       // cvt F_w
        long i = ((long)blk * 256 + t) * 8;
        float4 a = *reinterpret_cast<const float4*>(Fw + i);
        float4 c = *reinterpret_cast<const float4*>(Fw + i + 4);
        bf16x8 o;
        o[0] = (__bf16)a.x; o[1] = (__bf16)a.y; o[2] = (__bf16)a.z; o[3] = (__bf16)a.w;
        o[4] = (__bf16)c.x; o[5] = (__bf16)c.y; o[6] = (__bf16)c.z; o[7] = (__bf16)c.w;
        *reinterpret_cast<bf16x8*>(f_bf + i) = o;
    } else if (blk < 768) {                // transpose-cvt G_w: gt[k][h] = G[h][k]
        const int id = blk - 512;
        const int bx = (id & 15) * 64;
        const int by = (id >> 4) * 64;
        const int tr = t >> 4;
        const int tc = (t & 15) * 4;
#pragma unroll
        for (int i = 0; i < 4; i++) {
            float4 v = *reinterpret_cast<const float4*>(&Gw[(size_t)(by + tr + i * 16) * H + bx + tc]);
            tile[tr + i * 16][tc + 0] = v.x;
            tile[tr + i * 16][tc + 1] = v.y;
            tile[tr + i * 16][tc + 2] = v.z;
            tile[tr + i * 16][tc + 3] = v.w;
        }
        __syncthreads();
        const int wr = t >> 2;
        const int wc = (t & 3) * 16;
        bf16x8 o0, o1;
#pragma unroll
        for (int j = 0; j < 8; j++) o0[j] = (__bf16)tile[wc + j][wr];
#pragma unroll
        for (int j = 0; j < 8; j++) o1[j] = (__bf16)tile[wc + 8 + j][wr];
        *reinterpret_cast<bf16x8*>(&gt_bf[(size_t)(bx + wr) * H + by + wc]) = o0;
        *reinterpret_cast<bf16x8*>(&gt_bf[(size_t)(bx + wr) * H + by + wc + 8]) = o1;
    } else {                               // gemv b2[o] = Fw[o,:]·Gb + Fb[o]
        const int o = blk - 768;
        float s = 0.f;
        for (int h = t; h < H; h += 256) s += Fw[(size_t)o * H + h] * Gb[h];
#pragma unroll
        for (int off = 32; off > 0; off >>= 1) s += __shfl_xor(s, off);
        __shared__ float ss[4];
        if ((t & 63) == 0) ss[t >> 6] = s;
        __syncthreads();
        if (t == 0) b2[o] = ss[0] + ss[1] + ss[2] + ss[3] + Fb[o];
    }
}

// ---------------------------------------------------------------------------
// D2 (independent): GEMM0 W[o][k]=sum_h F[o][h]*Gt[k][h] (0..255) |
// transpose-cvt hidden -> Xt[b][h][s] (256..2303) | softmax (2304..10495)
// ---------------------------------------------------------------------------
__global__ __launch_bounds__(256) void mid_kernel(
    const __bf16* __restrict__ f_bf, const __bf16* __restrict__ gt_bf,
    __bf16* __restrict__ Wm,
    const float* __restrict__ hidden, __bf16* __restrict__ xt,
    const float* __restrict__ R, const float* __restrict__ mask,
    __bf16* __restrict__ P, int H, int S) {
    const int blk = blockIdx.x;
    const int t = threadIdx.x;

    if (blk < 256) {  // GEMM0 64x64 tile: direct write Wm[o][k]
        __shared__ __bf16 As[64 * 64];
        __shared__ __bf16 Bs[64 * 64];
        const int lane = t & 63;
        const int wave = t >> 6;
        const int lane31 = lane & 31;
        const int hi = lane >> 5;
        const int wm = (wave >> 1) * 32;
        const int wn = (wave & 1) * 32;
        const int bm = (blk >> 4) * 64;
        const int bn = (blk & 15) * 64;

        const int rsub = lane >> 3;
        const int csub = lane & 7;
        const int lchunk = csub ^ rsub;
        const __bf16* ga0 = f_bf + (size_t)(bm + wave * 16 + rsub) * H + lchunk * 8;
        const __bf16* gb0 = gt_bf + (size_t)(bn + wave * 16 + rsub) * H + lchunk * 8;

        f32x16 acc = (f32x16)(0.f);
        for (int kt = 0; kt < H; kt += 64) {
            __syncthreads();
#pragma unroll
            for (int c = 0; c < 2; c++)
                __builtin_amdgcn_global_load_lds(GPTR(ga0 + (size_t)(c * 8) * H + kt),
                                                 LPTR(&As[(wave * 16 + c * 8) * 64]), 16, 0, 0);
#pragma unroll
            for (int c = 0; c < 2; c++)
                __builtin_amdgcn_global_load_lds(GPTR(gb0 + (size_t)(c * 8) * H + kt),
                                                 LPTR(&Bs[(wave * 16 + c * 8) * 64]), 16, 0, 0);
            __syncthreads();
#pragma unroll
            for (int s = 0; s < 4; s++) {
                const int ra = wm + lane31;
                const int rb = wn + lane31;
                bf16x8 af = *reinterpret_cast<const bf16x8*>(
                    &As[ra * 64 + (((2 * s + hi) ^ (ra & 7)) << 3)]);
                bf16x8 bfr = *reinterpret_cast<const bf16x8*>(
                    &Bs[rb * 64 + (((2 * s + hi) ^ (rb & 7)) << 3)]);
                acc = __builtin_amdgcn_mfma_f32_32x32x16_bf16(af, bfr, acc, 0, 0, 0);
            }
        }
        const int cm = bm + wm;
        const int cn = bn + wn + lane31;
#pragma unroll
        for (int rq = 0; rq < 4; rq++) {
            const int rbase = rq * 8 + 4 * hi;
#pragma unroll
            for (int rr = 0; rr < 4; rr++)
                Wm[(size_t)(cm + rbase + rr) * H + cn] = (__bf16)acc[rq * 4 + rr];
        }
    } else if (blk < 2304) {  // transpose-cvt hidden[b]: Xt[b][h][s]
        __shared__ float tile[64][65];
        const int id = blk - 256;
        const int b = id >> 9;
        const int tid = id & 511;
        const int by = (tid >> 4) * 64;    // s-base
        const int bx = (tid & 15) * 64;    // h-base
        const float* x = hidden + (size_t)b * S * H;
        __bf16* y = xt + (size_t)b * H * S;
        const int tr = t >> 4;
        const int tc = (t & 15) * 4;
#pragma unroll
        for (int i = 0; i < 4; i++) {
            float4 v = *reinterpret_cast<const float4*>(&x[(size_t)(by + tr + i * 16) * H + bx + tc]);
            tile[tr + i * 16][tc + 0] = v.x;
            tile[tr + i * 16][tc + 1] = v.y;
            tile[tr + i * 16][tc + 2] = v.z;
            tile[tr + i * 16][tc + 3] = v.w;
        }
        __syncthreads();
        const int wr = t >> 2;
        const int wc = (t & 3) * 16;
        bf16x8 o0, o1;
#pragma unroll
        for (int j = 0; j < 8; j++) o0[j] = (__bf16)tile[wc + j][wr];
#pragma unroll
        for (int j = 0; j < 8; j++) o1[j] = (__bf16)tile[wc + 8 + j][wr];
        *reinterpret_cast<bf16x8*>(&y[(size_t)(bx + wr) * S + by + wc]) = o0;
        *reinterpret_cast<bf16x8*>(&y[(size_t)(bx + wr) * S + by + wc + 8]) = o1;
    } else {          // softmax row
        const int id = blk - 2304;
        const int b = id >> 11;
        const int q = id & 2047;
        const int lane = t & 63, wave = t >> 6;
        const float* rrow = R + (size_t)q * S;
        const float* mrow = mask + ((size_t)b * S + q) * (size_t)S;
        __bf16* prow = P + ((size_t)b * S + q) * (size_t)S;

        float v[8];
#pragma unroll
        for (int i = 0; i < 2; i++) {
            float4 r4 = *reinterpret_cast<const float4*>(rrow + t * 8 + i * 4);
            float4 m4 = *reinterpret_cast<const float4*>(mrow + t * 8 + i * 4);
            v[i * 4 + 0] = r4.x + m4.x;
            v[i * 4 + 1] = r4.y + m4.y;
            v[i * 4 + 2] = r4.z + m4.z;
            v[i * 4 + 3] = r4.w + m4.w;
        }
        float mx = v[0];
#pragma unroll
        for (int i = 1; i < 8; i++) mx = fmaxf(mx, v[i]);
#pragma unroll
        for (int off = 32; off > 0; off >>= 1) mx = fmaxf(mx, __shfl_xor(mx, off));
        __shared__ float smax[4], ssum[4];
        if (lane == 0) smax[wave] = mx;
        __syncthreads();
        mx = fmaxf(fmaxf(smax[0], smax[1]), fmaxf(smax[2], smax[3]));
        float sum = 0.f;
#pragma unroll
        for (int i = 0; i < 8; i++) { v[i] = __expf(v[i] - mx); sum += v[i]; }
#pragma unroll
        for (int off = 32; off > 0; off >>= 1) sum += __shfl_xor(sum, off);
        if (lane == 0) ssum[wave] = sum;
        __syncthreads();
        sum = ssum[0] + ssum[1] + ssum[2] + ssum[3];
        const float inv = 1.0f / sum;
        bf16x8 o;
#pragma unroll
        for (int i = 0; i < 8; i++) o[i] = (__bf16)(v[i] * inv);
        *reinterpret_cast<bf16x8*>(prow + t * 8) = o;
    }
}

// ---------------------------------------------------------------------------
// NT GEMM, DOUBLE-BUFFERED / ONE-BARRIER K-loop:
//   C[m,n] = sum_k A[m,k]*B[n,k] (+ bias[n])
// 128x128 tile, BK=64, 256 threads = 4 waves of 64x64 (2x2 mfma_f32_32x32x16).
// K-loop: stage(p^1, k+64) -> compute(p) -> ONE __syncthreads() -> flip.
//   The barrier's vmcnt(0) drain lands AFTER a full compute phase of head
//   start (vs the 2-barrier loop where the drain immediately follows the DMA
//   issues — the ~300-500 cyc exposed stall behind the 52-54 us plateau).
//   Safety: barrier at end of iter i guarantees (a) all reads of buf p_i done
//   before iter i+1 overwrites it, (b) DMAs to buf p_i^1 drained before read.
// LDS 64 KB -> 2 blocks/CU; grid 512 = exactly 2/CU (8 waves, no tail).
// Staging: global_load_lds w16, row-contiguous, XOR chunks (phys=log^(row&7)).
// SWZMODE 1 (T1): id&7 = XCD -> (b, m-half). SWZMODE 2 (T2): id&7 -> m-range.
// ---------------------------------------------------------------------------
template <bool CFLOAT, bool BIAS, int SWZMODE>
__global__ __launch_bounds__(256) void gemm_nt_kernel(
    const __bf16* __restrict__ A, const __bf16* __restrict__ B,
    const float* __restrict__ bias, void* __restrict__ Cv,
    int K, int lda, int ldb, int ldc,
    long strideA, long strideB, long strideC) {
    const int t = threadIdx.x;
    const int lane = t & 63;
    const int wave = t >> 6;             // 0..3
    const int lane31 = lane & 31;
    const int hi = lane >> 5;
    const int wm = (wave >> 1) * 64;
    const int wn = (wave & 1) * 64;
    int bm, bn, bz;
    if constexpr (SWZMODE == 1) {
        // 512 = 8 xcd * 64 slots; xcd -> (b = xcd>>1, m-half = xcd&1)
        const int id = blockIdx.x;
        const int xcd = id & 7;
        const int slot = id >> 3;
        bz = xcd >> 1;
        bm = ((xcd & 1) * 8 + (slot >> 3)) * 128;
        bn = (slot & 7) * 128;
    } else {
        const int id = blockIdx.x;
        const int xcd = id & 7;
        const int slot = id >> 3;
        bz = 0;
        bm = (xcd * 8 + (slot >> 3)) * 128;
        bn = (slot & 7) * 128;
    }

    A += (size_t)bz * strideA;
    B += (size_t)bz * strideB;

    __shared__ __bf16 smem[32768];       // 64 KB: buf p at p*16384 (As 8192|Bs 8192)

    // staging: wave w -> A rows w*32..+31 (4 DMAs), B rows w*32..+31 (4 DMAs)
    const int rsub = lane >> 3;
    const int csub = lane & 7;
    const int lchunk = csub ^ rsub;
    const __bf16* ga0 = A + (size_t)(bm + wave * 32 + rsub) * lda + lchunk * 8;
    const __bf16* gb0 = B + (size_t)(bn + wave * 32 + rsub) * ldb + lchunk * 8;

    auto stage = [&](int p, int kt) {
        __bf16* As_ = smem + p * 16384;
        __bf16* Bs_ = smem + p * 16384 + 8192;
#pragma unroll
        for (int c = 0; c < 4; c++)
            __builtin_amdgcn_global_load_lds(GPTR(ga0 + (size_t)(c * 8) * lda + kt),
                                             LPTR(&As_[(wave * 32 + c * 8) * 64]), 16, 0, 0);
#pragma unroll
        for (int c = 0; c < 4; c++)
            __builtin_amdgcn_global_load_lds(GPTR(gb0 + (size_t)(c * 8) * ldb + kt),
                                             LPTR(&Bs_[(wave * 32 + c * 8) * 64]), 16, 0, 0);
    };

    f32x16 acc[2][2];
#pragma unroll
    for (int i = 0; i < 2; i++)
#pragma unroll
        for (int j = 0; j < 2; j++) acc[i][j] = (f32x16)(0.f);

    stage(0, 0);
    __syncthreads();                     // first tile drain (exposed once)
    int p = 0;
    for (int kt = 0; kt < K; kt += 64) {
        if (kt + 64 < K) stage(p ^ 1, kt + 64);  // prefetch BEFORE compute
        const __bf16* As = smem + p * 16384;
        const __bf16* Bs = smem + p * 16384 + 8192;
#pragma unroll
        for (int s = 0; s < 4; s++) {
            bf16x8 af[2], bfr[2];
#pragma unroll
            for (int mi = 0; mi < 2; mi++) {
                const int r = wm + mi * 32 + lane31;
                af[mi] = *reinterpret_cast<const bf16x8*>(
                    &As[r * 64 + (((2 * s + hi) ^ (r & 7)) << 3)]);
            }
#pragma unroll
            for (int ni = 0; ni < 2; ni++) {
                const int r = wn + ni * 32 + lane31;
                bfr[ni] = *reinterpret_cast<const bf16x8*>(
                    &Bs[r * 64 + (((2 * s + hi) ^ (r & 7)) << 3)]);
            }
#pragma unroll
            for (int mi = 0; mi < 2; mi++)
#pragma unroll
                for (int ni = 0; ni < 2; ni++)
                    acc[mi][ni] = __builtin_amdgcn_mfma_f32_32x32x16_bf16(af[mi], bfr[ni], acc[mi][ni], 0, 0, 0);
        }
        __syncthreads();                 // ONE barrier: reads done + prefetch drained
        p ^= 1;
    }

    // Epilogue. C/D: col = lane&31, row = (reg&3)+8*(reg>>2)+4*(lane>>5)
    __bf16* Cb = (__bf16*)Cv + (size_t)bz * strideC;
    float* Cf = (float*)Cv + (size_t)bz * strideC;
#pragma unroll
    for (int mi = 0; mi < 2; mi++)
#pragma unroll
        for (int ni = 0; ni < 2; ni++) {
            const int cm = bm + wm + mi * 32;
            const int cn = bn + wn + ni * 32 + lane31;
            const float bv = BIAS ? bias[cn] : 0.0f;
#pragma unroll
            for (int rq = 0; rq < 4; rq++) {
                const int rbase = rq * 8 + 4 * hi;
                if constexpr (CFLOAT) {
#pragma unroll
                    for (int rr = 0; rr < 4; rr++)
                        Cf[(size_t)(cm + rbase + rr) * ldc + cn] = acc[mi][ni][rq * 4 + rr] + bv;
                } else {
#pragma unroll
                    for (int rr = 0; rr < 4; rr++)
                        Cb[(size_t)(cm + rbase + rr) * ldc + cn] = (__bf16)(acc[mi][ni][rq * 4 + rr] + bv);
                }
            }
        }
}

// ---------------------------------------------------------------------------
// Pipeline (out = (P @ X) W^T + b2, W = F G, b2 = F G_b + F_b):
//   D1[cvtF|transpG|gemv] -> D2[GEMM0->W || transp-hidden || softmax]
//   -> T1 = P @ Xt (bf16) -> T2 = T1 @ W^T + b2 (fp32)
// ---------------------------------------------------------------------------
extern "C" void kernel_launch(void* const* d_in, const int* in_sizes, int n_in,
                              void* d_out, int out_size, void* d_ws, size_t ws_size,
                              hipStream_t stream) {
    const float* hidden = (const float*)d_in[0];
    const float* mask   = (const float*)d_in[1];
    const float* R      = (const float*)d_in[2];
    const float* G_w    = (const float*)d_in[3];
    const float* G_b    = (const float*)d_in[4];
    const float* F_w    = (const float*)d_in[5];
    const float* F_b    = (const float*)d_in[6];
    float* out = (float*)d_out;

    constexpr int B = 4, S = 2048, H = 1024;
    char* ws = (char*)d_ws;
    __bf16* xt    = (__bf16*)(ws);                   // 16 MB  Xt[b][h][s]
    __bf16* t1    = (__bf16*)(ws + (16ll << 20));    // 16 MB  T1[b][q][h]
    __bf16* probs = (__bf16*)(ws + (32ll << 20));    // 32 MB
    __bf16* f_bf  = (__bf16*)(ws + (64ll << 20));    // 2 MB
    __bf16* gt_bf = (__bf16*)(ws + (66ll << 20));    // 2 MB
    __bf16* Wm    = (__bf16*)(ws + (68ll << 20));    // 2 MB
    float*  b2    = (float*)(ws + (70ll << 20));     // 4 KB

    pre_kernel<<<1792, 256, 0, stream>>>(F_w, f_bf, G_w, gt_bf, G_b, F_b, b2, H);

    mid_kernel<<<10496, 256, 0, stream>>>(f_bf, gt_bf, Wm, hidden, xt,
                                          R, mask, probs, H, S);

    // T1[b][q][h] = sum_s probs[b][q][s] * Xt[b][h][s]   (bf16 out, XCD swizzle)
    gemm_nt_kernel<false, false, 1><<<512, 256, 0, stream>>>(
        probs, xt, nullptr, t1, S, S, S, H,
        (long)S * S, (long)H * S, (long)S * H);

    // out[m][o] = sum_h T1[m][h] * W[o][h] + b2[o]   (m = b*S+q flat, fp32 out)
    gemm_nt_kernel<true, true, 2><<<512, 256, 0, stream>>>(
        t1, Wm, b2, out, H, H, H, H, 0, 0, 0);
}